// Round 6
// baseline (253.376 us; speedup 1.0000x reference)
//
#include <hip/hip_runtime.h>
#include <cstddef>

#define BB 8
#define SS 2048
#define DD 512
#define MM (BB * SS)

typedef __attribute__((ext_vector_type(8))) short bf16x8;
typedef __attribute__((ext_vector_type(4))) float f32x4;
typedef __attribute__((ext_vector_type(4))) unsigned short u16x4;

__device__ __forceinline__ f32x4 mfma16(bf16x8 a, bf16x8 b, f32x4 c) {
  return __builtin_amdgcn_mfma_f32_16x16x32_bf16(a, b, c, 0, 0, 0);
}
__device__ __forceinline__ unsigned short f2bf(float f) {
  unsigned int u = __float_as_uint(f);
  u += 0x7fffu + ((u >> 16) & 1u);
  return (unsigned short)(u >> 16);
}
__device__ __forceinline__ void gld16(const void* g, void* l) {
  __builtin_amdgcn_global_load_lds((const __attribute__((address_space(1))) void*)g,
                                   (__attribute__((address_space(3))) void*)l, 16, 0, 0);
}

// ---------------- fused: 3x weight fp32->bf16 convert + per-batch mask scan ----------------
__global__ void prep_kernel(const float* __restrict__ Wq, const float* __restrict__ Wk,
                            const float* __restrict__ Wv, unsigned short* __restrict__ Wqb,
                            unsigned short* __restrict__ Wkb, unsigned short* __restrict__ Wvb,
                            const int* __restrict__ mask, int* __restrict__ posArr,
                            int* __restrict__ nbArr) {
  __shared__ int part[256];
  const int bx = blockIdx.x;
  const int t = threadIdx.x;
  if (bx < 768) {
    const int which = bx >> 8;
    const float* s = which == 0 ? Wq : (which == 1 ? Wk : Wv);
    unsigned short* d = which == 0 ? Wqb : (which == 1 ? Wkb : Wvb);
    const int i = (bx & 255) * 256 + t;
    f32x4 v = reinterpret_cast<const f32x4*>(s)[i];
    u16x4 o;
    o[0] = f2bf(v[0]); o[1] = f2bf(v[1]); o[2] = f2bf(v[2]); o[3] = f2bf(v[3]);
    reinterpret_cast<u16x4*>(d)[i] = o;
    return;
  }
  const int b = bx - 768;
  int m[8], c = 0;
#pragma unroll
  for (int e = 0; e < 8; ++e) {
    m[e] = mask[b * SS + t * 8 + e];
    c += (m[e] != 0);
  }
  int v = c;
  part[t] = v;
  __syncthreads();
  for (int off = 1; off < 256; off <<= 1) {
    int u = (t >= off) ? part[t - off] : 0;
    __syncthreads();
    v += u;
    part[t] = v;
    __syncthreads();
  }
  int base = v - c;
#pragma unroll
  for (int e = 0; e < 8; ++e) {
    posArr[b * SS + t * 8 + e] = m[e] ? base : -1;
    if (m[e]) ++base;
  }
  if (t == 255) nbArr[b] = part[255];
}

// ---------------- x fp32->bf16 convert + compacted-row gather ----------------
__global__ void cvtx_kernel(const float* __restrict__ x, const int* __restrict__ posArr,
                            unsigned short* __restrict__ Xb, unsigned short* __restrict__ Xc) {
  const int gid = blockIdx.x * 256 + threadIdx.x;  // over MM*DD/4
  const int col4 = gid & 127;
  const int row = gid >> 7;
  f32x4 v = reinterpret_cast<const f32x4*>(x)[gid];
  u16x4 o;
  o[0] = f2bf(v[0]); o[1] = f2bf(v[1]); o[2] = f2bf(v[2]); o[3] = f2bf(v[3]);
  reinterpret_cast<u16x4*>(Xb)[gid] = o;
  const int p = posArr[row];
  if (p >= 0) {
    const int b = row >> 11;
    reinterpret_cast<u16x4*>(Xc)[((size_t)(b << 11) + p) * 128 + col4] = o;
  }
}

// ---------------- fused QKV GEMM; K/V only over compacted rows ----------------
__global__ __launch_bounds__(256, 2) void qkv_gemm_kernel(
    const unsigned short* __restrict__ Xb, const unsigned short* __restrict__ Xc,
    const unsigned short* __restrict__ W0, const unsigned short* __restrict__ W1,
    const unsigned short* __restrict__ W2, const float* __restrict__ b0,
    const float* __restrict__ b1, const float* __restrict__ b2,
    unsigned short* __restrict__ Qb, unsigned short* __restrict__ Kc,
    unsigned short* __restrict__ Vc, const int* __restrict__ nbArr) {
  __shared__ unsigned char a_lds[128 * 128];
  __shared__ unsigned char b_lds[128 * 128];
  const int which = blockIdx.z;
  int m0;
  const unsigned short* X;
  unsigned short* out;
  if (which == 0) {
    X = Xb; out = Qb; m0 = blockIdx.x * 128;
  } else {
    const int b = blockIdx.x >> 4, mt0 = blockIdx.x & 15;
    if (mt0 * 128 >= nbArr[b]) return;
    X = Xc; out = (which == 1) ? Kc : Vc; m0 = b * SS + mt0 * 128;
  }
  const unsigned short* W = which == 0 ? W0 : (which == 1 ? W1 : W2);
  const float* bias = which == 0 ? b0 : (which == 1 ? b1 : b2);
  const int tid = threadIdx.x;
  const int w = tid >> 6, l = tid & 63, lr = l & 15, hi = l >> 4;
  const int n0 = blockIdx.y * 128;
  const int wm = (w >> 1) * 64, wn = (w & 1) * 64;
  const int srow = l >> 3, gchunk = (l & 7) ^ (srow & 7);

  f32x4 acc[4][4];
#pragma unroll
  for (int mt = 0; mt < 4; ++mt)
#pragma unroll
    for (int nt = 0; nt < 4; ++nt) acc[mt][nt] = (f32x4){0.f, 0.f, 0.f, 0.f};

  const unsigned short* ga = X + (size_t)(m0 + w * 32 + srow) * DD + gchunk * 8;
  const unsigned short* gb = W + (size_t)(n0 + w * 32 + srow) * DD + gchunk * 8;

  for (int k0 = 0; k0 < DD; k0 += 64) {
#pragma unroll
    for (int ii = 0; ii < 4; ++ii) {
      gld16(ga + (size_t)ii * 8 * DD + k0, &a_lds[(w * 4 + ii) * 1024]);
      gld16(gb + (size_t)ii * 8 * DD + k0, &b_lds[(w * 4 + ii) * 1024]);
    }
    __syncthreads();
#pragma unroll
    for (int dkl = 0; dkl < 2; ++dkl) {
      const int gc = dkl * 4 + hi;
      bf16x8 af[4], bfr[4];
#pragma unroll
      for (int mt = 0; mt < 4; ++mt) {
        const int row = wm + mt * 16 + lr;
        af[mt] = *reinterpret_cast<const bf16x8*>(
            &a_lds[row * 128 + ((gc ^ (row & 7)) * 16)]);
      }
#pragma unroll
      for (int nt = 0; nt < 4; ++nt) {
        const int row = wn + nt * 16 + lr;
        bfr[nt] = *reinterpret_cast<const bf16x8*>(
            &b_lds[row * 128 + ((gc ^ (row & 7)) * 16)]);
      }
#pragma unroll
      for (int mt = 0; mt < 4; ++mt)
#pragma unroll
        for (int nt = 0; nt < 4; ++nt)
          acc[mt][nt] = mfma16(af[mt], bfr[nt], acc[mt][nt]);
    }
    __syncthreads();
  }

#pragma unroll
  for (int nt = 0; nt < 4; ++nt) {
    const int col = n0 + wn + nt * 16 + lr;
    const float bv = bias[col];
#pragma unroll
    for (int mt = 0; mt < 4; ++mt)
#pragma unroll
      for (int r = 0; r < 4; ++r) {
        const int row = m0 + wm + mt * 16 + hi * 4 + r;
        out[(size_t)row * DD + col] = f2bf(acc[mt][nt][r] + bv);
      }
  }
}

// ---------------- V tiled-transpose (compacted rows, zero-filled tail) ----------------
__global__ void vtrans_kernel(const unsigned short* __restrict__ Vc,
                              const int* __restrict__ nbArr,
                              unsigned short* __restrict__ VT2) {
  __shared__ unsigned short t[64][72];
  const int b = blockIdx.z;
  const int kt = blockIdx.x;
  const int nb = nbArr[b];
  if (kt * 64 >= nb) return;
  const int d0 = blockIdx.y * 64;
  const int tid = threadIdx.x;
  const int c = tid & 63, rg = tid >> 6;
#pragma unroll
  for (int i = 0; i < 16; ++i) {
    const int row = rg * 16 + i;
    const int s = kt * 64 + row;
    t[row][c] = (s < nb) ? Vc[((size_t)b * SS + s) * DD + d0 + c] : (unsigned short)0;
  }
  __syncthreads();
#pragma unroll
  for (int i = 0; i < 16; ++i) {
    const int ix = i * 256 + tid;
    const int jj = ix & 7;
    const int dl = (ix >> 3) & 63;
    const int cc = ix >> 9;
    VT2[(((size_t)(b * 32 + kt) * 8 + cc) * 512 + d0 + dl) * 8 + jj] =
        t[cc * 8 + jj][dl];
  }
}

// ---------------- flash attention: key-split-K, d-split PV across waves ----------------
__global__ __launch_bounds__(256, 2) void attn_kernel(
    const unsigned short* __restrict__ Q, const unsigned short* __restrict__ Kc,
    const unsigned short* __restrict__ VT2, const int* __restrict__ nbArr,
    float* __restrict__ Out, float* __restrict__ Apart, float* __restrict__ mlpart) {
  __shared__ unsigned char k_lds[32 * 1024];
  __shared__ unsigned char vt_lds[4 * 512 * 16];
  __shared__ unsigned short pbuf[4][16][32];  // [q-tile][row][key] bf16
  __shared__ __align__(16) float alds[68];    // alpha[64] + flags[4]
  const int tid = threadIdx.x;
  const int w = tid >> 6, l = tid & 63, lr = l & 15, hi = l >> 4;
  const int bid = blockIdx.x;
  const int b = bid & 7;
  const int qt = (bid >> 3) >> 1;
  const int sp = (bid >> 3) & 1;
  const int q0 = qt * 64 + w * 16;  // phase-1 q rows for this wave
  const float scale = 0.044194173824159216f;  // 1/sqrt(512)

  const int nb = nbArr[b];
  const int ntile = (nb + 31) >> 5;
  const int half = (ntile + 1) >> 1;
  const int lo = sp == 0 ? 0 : half;
  const int hi_t = sp == 0 ? half : ntile;

  const unsigned short* __restrict__ Qb = Q + (size_t)b * SS * DD;
  const unsigned short* __restrict__ Kb = Kc + (size_t)b * SS * DD;
  const unsigned short* __restrict__ Vb = VT2 + (size_t)b * SS * DD;

  bf16x8 qf[16];
#pragma unroll
  for (int dk = 0; dk < 16; ++dk)
    qf[dk] = *reinterpret_cast<const bf16x8*>(
        &Qb[(size_t)(q0 + lr) * DD + dk * 32 + hi * 8]);

  // O tile: rows mt*16+hi*4+r (all 64 block q-rows), cols w*128+nt*16+lr
  f32x4 oacc[32];
#pragma unroll
  for (int i = 0; i < 32; ++i) oacc[i] = (f32x4){0.f, 0.f, 0.f, 0.f};
  float mrow[4], lrow[4];
#pragma unroll
  for (int r = 0; r < 4; ++r) {
    mrow[r] = -10000.0f;
    lrow[r] = 0.0f;
  }

  auto stageK = [&](int t) {
#pragma unroll
    for (int r = 0; r < 8; ++r) {
      const int row = w * 8 + r;
      const int ch = (l & 56) | ((l ^ row) & 7);
      gld16(Kb + (size_t)(t * 32 + row) * DD + ch * 8, &k_lds[row * 1024]);
    }
  };
  auto stageV = [&](int t) {
    const size_t vbase = ((size_t)((t >> 1) * 8 + (t & 1) * 4 + w) * 512);
#pragma unroll
    for (int g = 0; g < 8; ++g)
      gld16(Vb + (vbase + g * 64 + l) * 8, &vt_lds[(w * 512 + g * 64) * 16]);
  };

  if (lo < hi_t) { stageK(lo); stageV(lo); }

  for (int t = lo; t < hi_t; ++t) {
    __syncthreads();  // A: K(t), V(t) landed

    // ---- phase 1: S = Q @ K^T, online softmax, P+alpha to LDS ----
    f32x4 sacc[2];
#pragma unroll
    for (int nt = 0; nt < 2; ++nt) sacc[nt] = (f32x4){0.f, 0.f, 0.f, 0.f};
#pragma unroll
    for (int dk = 0; dk < 16; ++dk) {
#pragma unroll
      for (int nt = 0; nt < 2; ++nt) {
        const int row = nt * 16 + lr;
        const int c = dk * 4 + hi;
        bf16x8 bk = *reinterpret_cast<const bf16x8*>(
            &k_lds[row * 1024 + ((c & ~7) | ((c ^ row) & 7)) * 16]);
        sacc[nt] = mfma16(qf[dk], bk, sacc[nt]);
      }
    }
    float s[2][4];
#pragma unroll
    for (int nt = 0; nt < 2; ++nt) {
      const int j = t * 32 + nt * 16 + lr;
      const bool ok = j < nb;
#pragma unroll
      for (int r = 0; r < 4; ++r)
        s[nt][r] = ok ? sacc[nt][r] * scale : -10000.0f;
    }
    float mnew[4], alpha[4];
#pragma unroll
    for (int r = 0; r < 4; ++r) {
      float mx = fmaxf(s[0][r], s[1][r]);
#pragma unroll
      for (int off = 1; off < 16; off <<= 1) mx = fmaxf(mx, __shfl_xor(mx, off));
      mnew[r] = fmaxf(mrow[r], mx);
      alpha[r] = __expf(mrow[r] - mnew[r]);
      mrow[r] = mnew[r];
    }
    float rs[4] = {0.f, 0.f, 0.f, 0.f};
#pragma unroll
    for (int nt = 0; nt < 2; ++nt)
#pragma unroll
      for (int r = 0; r < 4; ++r) {
        float p = __expf(s[nt][r] - mnew[r]);
        s[nt][r] = p;
        rs[r] += p;
      }
#pragma unroll
    for (int r = 0; r < 4; ++r) {
      float tt = rs[r];
#pragma unroll
      for (int off = 1; off < 16; off <<= 1) tt += __shfl_xor(tt, off);
      lrow[r] = lrow[r] * alpha[r] + tt;
    }
#pragma unroll
    for (int nt = 0; nt < 2; ++nt)
#pragma unroll
      for (int r = 0; r < 4; ++r)
        pbuf[w][hi * 4 + r][nt * 16 + lr] = f2bf(s[nt][r]);
    if (lr == 0)
      *reinterpret_cast<f32x4*>(&alds[w * 16 + hi * 4]) =
          (f32x4){alpha[0], alpha[1], alpha[2], alpha[3]};
    const float aprod = alpha[0] * alpha[1] * alpha[2] * alpha[3];
    unsigned long long bal = __ballot(aprod == 1.0f);
    if (l == 0) alds[64 + w] = (bal == ~0ull) ? 1.0f : 0.0f;

    __syncthreads();  // B: pbuf/alds ready, k_lds dead
    if (t + 1 < hi_t) stageK(t + 1);  // overlaps phase 2

    // ---- phase 2: O[64q x this wave's 128 d] += P @ V ----
    f32x4 fl = *reinterpret_cast<const f32x4*>(&alds[64]);
    bf16x8 af[4];
#pragma unroll
    for (int mt = 0; mt < 4; ++mt)
      af[mt] = *reinterpret_cast<const bf16x8*>(&pbuf[mt][lr][hi * 8]);
    if (fl[0] + fl[1] + fl[2] + fl[3] < 4.0f) {
#pragma unroll
      for (int mt = 0; mt < 4; ++mt) {
        f32x4 al = *reinterpret_cast<const f32x4*>(&alds[mt * 16 + hi * 4]);
#pragma unroll
        for (int nt = 0; nt < 8; ++nt)
#pragma unroll
          for (int r = 0; r < 4; ++r) oacc[mt * 8 + nt][r] *= al[r];
      }
    }
#pragma unroll
    for (int nt = 0; nt < 8; ++nt) {
      bf16x8 bv = *reinterpret_cast<const bf16x8*>(
          &vt_lds[(hi * 512 + w * 128 + nt * 16 + lr) * 16]);
#pragma unroll
      for (int mt = 0; mt < 4; ++mt)
        oacc[mt * 8 + nt] = mfma16(af[mt], bv, oacc[mt * 8 + nt]);
    }

    __syncthreads();  // C: vt_lds dead
    if (t + 1 < hi_t) stageV(t + 1);
  }

  // ---- epilogue ----
  float* Ap = sp == 0 ? Out : Apart;
#pragma unroll
  for (int mt = 0; mt < 4; ++mt)
#pragma unroll
    for (int nt = 0; nt < 8; ++nt)
#pragma unroll
      for (int r = 0; r < 4; ++r)
        Ap[((size_t)b * SS + qt * 64 + mt * 16 + hi * 4 + r) * DD + w * 128 +
           nt * 16 + lr] = oacc[mt * 8 + nt][r];
  if (lr == 0) {
#pragma unroll
    for (int r = 0; r < 4; ++r) {
      const size_t row = (size_t)sp * MM + b * SS + q0 + hi * 4 + r;
      mlpart[row * 2 + 0] = mrow[r];
      mlpart[row * 2 + 1] = lrow[r];
    }
  }
}

// ---------------- combine: in-place merge split0 (in Out) + split1 (Apart) ----------------
__global__ void combine_kernel(float* __restrict__ Out, const float* __restrict__ Apart,
                               const float* __restrict__ mlpart) {
  const int gid = blockIdx.x * 256 + threadIdx.x;
  const int row = gid >> 7;
  const float m1 = mlpart[(size_t)row * 2 + 0];
  const float l1 = mlpart[(size_t)row * 2 + 1];
  const float m2 = mlpart[((size_t)MM + row) * 2 + 0];
  const float l2 = mlpart[((size_t)MM + row) * 2 + 1];
  const float m = fmaxf(m1, m2);
  const float w1 = __expf(m1 - m), w2 = __expf(m2 - m);
  const float inv = 1.0f / (w1 * l1 + w2 * l2);
  f32x4 a1 = reinterpret_cast<f32x4*>(Out)[gid];
  f32x4 a2 = reinterpret_cast<const f32x4*>(Apart)[gid];
  f32x4 o;
#pragma unroll
  for (int e = 0; e < 4; ++e) o[e] = (w1 * a1[e] + w2 * a2[e]) * inv;
  reinterpret_cast<f32x4*>(Out)[gid] = o;
}

extern "C" void kernel_launch(void* const* d_in, const int* in_sizes, int n_in,
                              void* d_out, int out_size, void* d_ws, size_t ws_size,
                              hipStream_t stream) {
  const float* x = (const float*)d_in[0];
  const int* mask = (const int*)d_in[1];
  const float* Wq = (const float*)d_in[2];
  const float* bq = (const float*)d_in[3];
  const float* Wk = (const float*)d_in[4];
  const float* bk = (const float*)d_in[5];
  const float* Wv = (const float*)d_in[6];
  const float* bv = (const float*)d_in[7];
  float* out = (float*)d_out;

  // ws layout (<= ~82.4 MB):
  //   0-16   Qb     (live through attn)
  //   16-32  Kc     (live through attn)
  //   32-48  Xc     (dead after qkv) / VT2b (written by vtrans after qkv)
  //   48-64  Xb     (dead after qkv)
  //   64-80  Vc     (dead after vtrans)
  //   48-80  Apart  (attn split1 partial, aliases Xb+Vc)
  //   80-81.5 weights bf16
  //   82+    posArr (64KB), nbArr, mlpart (256KB)
  char* ws = (char*)d_ws;
  const size_t MB = 1024 * 1024;
  unsigned short* Qb = (unsigned short*)(ws);
  unsigned short* Kc = (unsigned short*)(ws + 16 * MB);
  unsigned short* Xc = (unsigned short*)(ws + 32 * MB);
  unsigned short* VT2b = (unsigned short*)(ws + 32 * MB);
  unsigned short* Xb = (unsigned short*)(ws + 48 * MB);
  unsigned short* Vc = (unsigned short*)(ws + 64 * MB);
  float* Apart = (float*)(ws + 48 * MB);
  unsigned short* Wqb = (unsigned short*)(ws + 80 * MB);
  unsigned short* Wkb = Wqb + 512 * 512;
  unsigned short* Wvb = Wkb + 512 * 512;
  int* posArr = (int*)(ws + 82 * MB);
  int* nbArr = (int*)(ws + 82 * MB + 65536);
  float* mlpart = (float*)(ws + 82 * MB + 128 * 1024);

  prep_kernel<<<776, 256, 0, stream>>>(Wq, Wk, Wv, Wqb, Wkb, Wvb, mask, posArr, nbArr);
  cvtx_kernel<<<8192, 256, 0, stream>>>(x, posArr, Xb, Xc);
  qkv_gemm_kernel<<<dim3(128, 4, 3), 256, 0, stream>>>(
      Xb, Xc, Wqb, Wkb, Wvb, bq, bk, bv, Qb, Kc, Vc, nbArr);
  vtrans_kernel<<<dim3(32, 8, 8), 256, 0, stream>>>(Vc, nbArr, VT2b);
  attn_kernel<<<512, 256, 0, stream>>>(Qb, Kc, VT2b, nbArr, out, Apart, mlpart);
  combine_kernel<<<8192, 256, 0, stream>>>(out, Apart, mlpart);
}